// Round 11
// baseline (181.641 us; speedup 1.0000x reference)
//
#include <hip/hip_runtime.h>
#include <hip/hip_fp8.h>
#include <cstdint>

// ---------------------------------------------------------------------------
// DeepFM forward, MI355X (R11).
//   Stage 1: prep — W1..W3 f32->fp4 W^T (pre-scaled 2^7) + gather (embed fp8,
//            lin, FM partials) + zero mlp-dot accumulator   [one kernel]
//   Stage 2: GEMM1, GEMM2 (A=fp8 acts, B=fp4 weights, 16x16x128 f8f6f4,
//            cbsz=0/blgp=4), bias+ReLU, fp8 out — LDS DOUBLE-BUFFER,
//            ONE barrier/iteration (R11 change)
//   Stage 3: GEMM3 with fused L4 dot (atomicAdd per sample; H3 never exists)
//   Stage 4: final — redundant-per-block S reduce + sigmoid.  5 nodes.
//
// R11 vs R10: BK=128 tiles kept (verified layouts) but double-buffered:
//   stage(k+1 -> buf^1); compute(buf); __syncthreads().
// The barrier's implicit vmcnt(0) drain now lands AFTER the MFMA block
// (load latency hidden under compute) and barrier count halves. R8 tried
// this with registers (VGPR cliff); R10 tried occupancy (neutral-negative);
// this is the LDS-resident variant at unchanged occupancy (48 KB -> 3
// blocks/CU, VGPR ~80). If neutral: the 2-barrier plateau is structural
// at this occupancy (m99/m100 transfers) -> declare practical roofline.
// Budget: ~100 us of dur_us is harness reset (268 MB ws poison + restores).
// ---------------------------------------------------------------------------

typedef float f32x4 __attribute__((ext_vector_type(4)));
typedef int i32x4 __attribute__((ext_vector_type(4)));
typedef int i32x8 __attribute__((ext_vector_type(8)));

#define GLOAD16(gptr, lptr)                                                \
  __builtin_amdgcn_global_load_lds(                                        \
      (const __attribute__((address_space(1))) void*)(gptr),               \
      (__attribute__((address_space(3))) void*)(lptr), 16, 0, 0)

// fp4 e2m1 encode (weights only; RNE; magnitudes 0,.5,1,1.5,2,3,4,6)
__device__ inline uint32_t f2fp4(float v) {
  uint32_t s = (__float_as_uint(v) >> 31) << 3;
  float a = fabsf(v);
  uint32_t m;
  if (a < 0.25f) m = 0;
  else if (a < 0.75f) m = 1;
  else if (a < 1.25f) m = 2;
  else if (a < 1.75f) m = 3;
  else if (a < 2.5f)  m = 4;
  else if (a < 3.5f)  m = 5;
  else if (a < 5.0f)  m = 6;
  else m = 7;
  return s | m;
}

// ---------------- workspace layout (bytes) ---------------------------------
static constexpr size_t OFF_LIN  = 0;                          // 16384 f32
static constexpr size_t OFF_PART = 65536;                      // 4096 f32
static constexpr size_t OFF_ACC  = 98304;                      // 16384 f32
static constexpr size_t OFF_EMB  = 262144;                     // B*512 fp8
static constexpr size_t OFF_H1   = OFF_EMB + 8388608ull;       // B*2048 fp8
static constexpr size_t OFF_H2   = OFF_H1 + 33554432ull;       // B*1024 fp8
static constexpr size_t OFF_W1T  = OFF_H2 + 16777216ull;       // 2048*512 fp4
static constexpr size_t OFF_W2T  = OFF_W1T + 524288ull;        // 1024*2048 fp4
static constexpr size_t OFF_W3T  = OFF_W2T + 1048576ull;       // 512*1024 fp4

// ---------------- Stage 1: fused prep (transpose + gather + zero) ----------
__global__ void prep(const float* __restrict__ W1, const float* __restrict__ W2,
                     const float* __restrict__ W3, uint8_t* __restrict__ W1T,
                     uint8_t* __restrict__ W2T, uint8_t* __restrict__ W3T,
                     const float* __restrict__ x, const float* __restrict__ fc,
                     const float* __restrict__ emb, uint8_t* __restrict__ ebf,
                     float* __restrict__ lin, float* __restrict__ partials,
                     float* __restrict__ dotacc) {
  __shared__ __align__(16) float smem[32 * 33];
  int blk = blockIdx.x;
  int tid = threadIdx.x;
  if (blk < 3584) {  // ---- transpose ----
    const float* W;
    uint8_t* WT;
    int K, N, bx, by;
    if (blk < 1024) {        // W1: K=512, N=2048
      W = W1; WT = W1T; K = 512; N = 2048; bx = blk & 63; by = blk >> 6;
    } else if (blk < 3072) { // W2: K=2048, N=1024
      int t = blk - 1024;
      W = W2; WT = W2T; K = 2048; N = 1024; bx = t & 31; by = t >> 5;
    } else {                 // W3: K=1024, N=512
      int t = blk - 3072;
      W = W3; WT = W3T; K = 1024; N = 512; bx = t & 15; by = t >> 4;
    }
    int tx = tid & 31, ty = tid >> 5;
    int n0 = bx * 32, k0 = by * 32;
#pragma unroll
    for (int i = ty; i < 32; i += 8)
      smem[i * 33 + tx] = W[(size_t)(k0 + i) * N + n0 + tx];
    __syncthreads();
    if (tx < 16) {
#pragma unroll
      for (int i = ty; i < 32; i += 8) {
        uint32_t lo = f2fp4(smem[(2 * tx) * 33 + i] * 128.f);
        uint32_t hi = f2fp4(smem[(2 * tx + 1) * 33 + i] * 128.f);
        WT[(size_t)(n0 + i) * (K >> 1) + (k0 >> 1) + tx] =
            (uint8_t)(lo | (hi << 4));
      }
    }
  } else if (blk < 7680) {  // ---- gather ----
    int gb = blk - 3584;
    int wv = tid >> 6, lane = tid & 63;
    int b = gb * 4 + wv;
    int f = lane >> 4;
    int idx = (int)x[b * 4 + f];               // raw index (NO offset) for emb
    const float* row = emb + (size_t)idx * 128 + (lane & 15) * 8;
    float4 v0 = ((const float4*)row)[0];
    float4 v1 = ((const float4*)row)[1];
    float s = v0.x + v0.y + v0.z + v0.w + v1.x + v1.y + v1.z + v1.w;
    float q = v0.x * v0.x + v0.y * v0.y + v0.z * v0.z + v0.w * v0.w +
              v1.x * v1.x + v1.y * v1.y + v1.z * v1.z + v1.w * v1.w;

    int lo = 0, hi = 0;
    lo = __builtin_amdgcn_cvt_pk_fp8_f32(v0.x, v0.y, lo, false);
    lo = __builtin_amdgcn_cvt_pk_fp8_f32(v0.z, v0.w, lo, true);
    hi = __builtin_amdgcn_cvt_pk_fp8_f32(v1.x, v1.y, hi, false);
    hi = __builtin_amdgcn_cvt_pk_fp8_f32(v1.z, v1.w, hi, true);
    int2 pk = make_int2(lo, hi);
    *(int2*)(ebf + (size_t)b * 512 + lane * 8) = pk;   // 8 B/lane coalesced

    float lp = 0.f;
    if ((lane & 15) == 0) {                    // fc lookup USES offsets
      int off = (f == 1) ? 31360 : (f == 2) ? 38167 : (f == 3) ? 38185 : 0;
      lp = fc[idx + off];
    }
#pragma unroll
    for (int m = 32; m; m >>= 1) {
      s += __shfl_xor(s, m);
      q += __shfl_xor(q, m);
      lp += __shfl_xor(lp, m);
    }
    float* pt = smem;
    if (lane == 0) {
      lin[b] = lp;
      pt[wv] = s * s - q;                      // per-sample FM term
    }
    __syncthreads();
    if (tid == 0) partials[gb] = pt[0] + pt[1] + pt[2] + pt[3];
  } else {  // ---- zero mlp-dot accumulator (16 blocks) ----
    int zb = blk - 7680;
    ((float4*)dotacc)[zb * 256 + tid] = make_float4(0.f, 0.f, 0.f, 0.f);
  }
}

// ---------------- Stage 2: mixed GEMM, C = relu(A*B + bias) ----------------
// A fp8 (stride K B), BT fp4 (stride K/2 B), C fp8 (stride N B).
// 128x128 tile, BK=128, LDS DOUBLE-BUFFER (2x24 KB = 48 KB, 3 blocks/CU).
// One __syncthreads per iteration; its vmcnt(0) drain lands after compute.
// As rows 128 B (8-chunk XOR swizzle), Bs rows 64 B (4-chunk XOR swizzle) —
// both verified conflict-free in earlier rounds. MFMA 16x16x128 f8f6f4:
// cbsz=0 (fp8 A), blgp=4 (fp4 B), scale_a=1, scale_b=2^-7 (undoes W
// pre-scale). XCD swizzle: same-A-strip blocks share bid%8. GX = N/128.
__global__ __launch_bounds__(256) void gemm_mx_relu(
    const uint8_t* __restrict__ A, const uint8_t* __restrict__ BT,
    const float* __restrict__ bias, uint8_t* __restrict__ C, int K, int N,
    int GX) {
  __shared__ __align__(16) uint8_t As[2][128][128];   // 32 KB
  __shared__ __align__(16) uint8_t Bs[2][128][64];    // 16 KB
  int bid = blockIdx.x;
  int by = (bid & 7) + ((bid >> 3) / GX) * 8;
  int bx = (bid >> 3) & (GX - 1);
  int tid = threadIdx.x;
  int wv = tid >> 6, lane = tid & 63;
  int m0 = by * 128, n0 = bx * 128;
  int mw = (wv >> 1) * 64, nw = (wv & 1) * 64;
  int ml = lane & 15, kg = lane >> 4;
  int Kb2 = K >> 1;
  int asrow = lane >> 3;                       // A staging: 8-row groups
  int ascol = ((lane & 7) ^ asrow) * 16;
  int bsrow = lane >> 2;                       // B staging: 16-row groups
  int bscol = ((lane & 3) ^ (bsrow & 3)) * 16;
  int pa0 = ((2 * kg) ^ (ml & 7)) * 16;        // A frag chunks
  int pa1 = ((2 * kg + 1) ^ (ml & 7)) * 16;
  int pb = (kg ^ (ml & 3)) * 16;               // B frag chunk

  f32x4 acc[4][4];
#pragma unroll
  for (int i = 0; i < 4; ++i)
#pragma unroll
    for (int j = 0; j < 4; ++j) acc[i][j] = (f32x4){0.f, 0.f, 0.f, 0.f};

  // prologue: stage tile 0 into buffer 0
#pragma unroll
  for (int r = 0; r < 4; ++r) {
    int g = r * 4 + wv;
    GLOAD16(A + (size_t)(m0 + 8 * g + asrow) * K + ascol, &As[0][8 * g][0]);
  }
#pragma unroll
  for (int r = 0; r < 2; ++r) {
    int g = r * 4 + wv;
    GLOAD16(BT + (size_t)(n0 + 16 * g + bsrow) * Kb2 + bscol,
            &Bs[0][16 * g][0]);
  }
  __syncthreads();

  for (int kt = 0; kt < K; kt += 128) {
    int cur = (kt >> 7) & 1;
    // stage tile k+1 into the other buffer (async; drained by end barrier)
    if (kt + 128 < K) {
#pragma unroll
      for (int r = 0; r < 4; ++r) {
        int g = r * 4 + wv;
        GLOAD16(A + (size_t)(m0 + 8 * g + asrow) * K + kt + 128 + ascol,
                &As[cur ^ 1][8 * g][0]);
      }
#pragma unroll
      for (int r = 0; r < 2; ++r) {
        int g = r * 4 + wv;
        GLOAD16(BT + (size_t)(n0 + 16 * g + bsrow) * Kb2 + ((kt + 128) >> 1) +
                    bscol,
                &Bs[cur ^ 1][16 * g][0]);
      }
    }

    // compute tile k from current buffer
    i32x4 z = (i32x4){0, 0, 0, 0};
    i32x8 af[4], bfr[4];
#pragma unroll
    for (int t = 0; t < 4; ++t) {
      int ra = mw + t * 16 + ml;
      i32x4 a0 = *(const i32x4*)&As[cur][ra][pa0];
      i32x4 a1 = *(const i32x4*)&As[cur][ra][pa1];
      af[t] = __builtin_shufflevector(a0, a1, 0, 1, 2, 3, 4, 5, 6, 7);
      i32x4 vb = *(const i32x4*)&Bs[cur][nw + t * 16 + ml][pb];
      bfr[t] = __builtin_shufflevector(vb, z, 0, 1, 2, 3, 4, 5, 6, 7);
    }
#pragma unroll
    for (int mt = 0; mt < 4; ++mt)
#pragma unroll
      for (int nt = 0; nt < 4; ++nt)
        acc[mt][nt] = __builtin_amdgcn_mfma_scale_f32_16x16x128_f8f6f4(
            af[mt], bfr[nt], acc[mt][nt],
            /*cbsz=fp8*/ 0, /*blgp=fp4*/ 4,
            0, 0x7F7F7F7F, 0, 0x78787878);
    __syncthreads();   // drains next-tile loads (post-compute) + reuse guard
  }

  // Epilogue: C/D layout col=lane&15, row=(lane>>4)*4+reg.
  int rbase = kg * 4;
#pragma unroll
  for (int nt = 0; nt < 4; ++nt) {
    int col = n0 + nw + nt * 16 + ml;
    float bv = bias[col];
#pragma unroll
    for (int mt = 0; mt < 4; ++mt) {
      int row = m0 + mw + mt * 16 + rbase;
      float v0 = acc[mt][nt][0] + bv, v1 = acc[mt][nt][1] + bv;
      float v2 = acc[mt][nt][2] + bv, v3 = acc[mt][nt][3] + bv;
      v0 = v0 > 0.f ? v0 : 0.f;
      v1 = v1 > 0.f ? v1 : 0.f;
      v2 = v2 > 0.f ? v2 : 0.f;
      v3 = v3 > 0.f ? v3 : 0.f;
      int w01 = __builtin_amdgcn_cvt_pk_fp8_f32(v0, v1, 0, false);
      int w23 = __builtin_amdgcn_cvt_pk_fp8_f32(v2, v3, 0, false);
      C[(size_t)(row + 0) * N + col] = (uint8_t)(w01 & 0xFF);
      C[(size_t)(row + 1) * N + col] = (uint8_t)((w01 >> 8) & 0xFF);
      C[(size_t)(row + 2) * N + col] = (uint8_t)(w23 & 0xFF);
      C[(size_t)(row + 3) * N + col] = (uint8_t)((w23 >> 8) & 0xFF);
    }
  }
}

// ---------------- Stage 3: GEMM3 + fused L4 partial dot --------------------
__global__ __launch_bounds__(256) void gemm_mx_dot(
    const uint8_t* __restrict__ A, const uint8_t* __restrict__ BT,
    const float* __restrict__ bias, const float* __restrict__ W4,
    float* __restrict__ dotacc, int K, int N, int GX) {
  __shared__ __align__(16) uint8_t As[2][128][128];
  __shared__ __align__(16) uint8_t Bs[2][128][64];
  int bid = blockIdx.x;
  int by = (bid & 7) + ((bid >> 3) / GX) * 8;
  int bx = (bid >> 3) & (GX - 1);
  int tid = threadIdx.x;
  int wv = tid >> 6, lane = tid & 63;
  int m0 = by * 128, n0 = bx * 128;
  int mw = (wv >> 1) * 64, nw = (wv & 1) * 64;
  int ml = lane & 15, kg = lane >> 4;
  int Kb2 = K >> 1;
  int asrow = lane >> 3;
  int ascol = ((lane & 7) ^ asrow) * 16;
  int bsrow = lane >> 2;
  int bscol = ((lane & 3) ^ (bsrow & 3)) * 16;
  int pa0 = ((2 * kg) ^ (ml & 7)) * 16;
  int pa1 = ((2 * kg + 1) ^ (ml & 7)) * 16;
  int pb = (kg ^ (ml & 3)) * 16;

  f32x4 acc[4][4];
#pragma unroll
  for (int i = 0; i < 4; ++i)
#pragma unroll
    for (int j = 0; j < 4; ++j) acc[i][j] = (f32x4){0.f, 0.f, 0.f, 0.f};

#pragma unroll
  for (int r = 0; r < 4; ++r) {
    int g = r * 4 + wv;
    GLOAD16(A + (size_t)(m0 + 8 * g + asrow) * K + ascol, &As[0][8 * g][0]);
  }
#pragma unroll
  for (int r = 0; r < 2; ++r) {
    int g = r * 4 + wv;
    GLOAD16(BT + (size_t)(n0 + 16 * g + bsrow) * Kb2 + bscol,
            &Bs[0][16 * g][0]);
  }
  __syncthreads();

  for (int kt = 0; kt < K; kt += 128) {
    int cur = (kt >> 7) & 1;
    if (kt + 128 < K) {
#pragma unroll
      for (int r = 0; r < 4; ++r) {
        int g = r * 4 + wv;
        GLOAD16(A + (size_t)(m0 + 8 * g + asrow) * K + kt + 128 + ascol,
                &As[cur ^ 1][8 * g][0]);
      }
#pragma unroll
      for (int r = 0; r < 2; ++r) {
        int g = r * 4 + wv;
        GLOAD16(BT + (size_t)(n0 + 16 * g + bsrow) * Kb2 + ((kt + 128) >> 1) +
                    bscol,
                &Bs[cur ^ 1][16 * g][0]);
      }
    }

    i32x4 z = (i32x4){0, 0, 0, 0};
    i32x8 af[4], bfr[4];
#pragma unroll
    for (int t = 0; t < 4; ++t) {
      int ra = mw + t * 16 + ml;
      i32x4 a0 = *(const i32x4*)&As[cur][ra][pa0];
      i32x4 a1 = *(const i32x4*)&As[cur][ra][pa1];
      af[t] = __builtin_shufflevector(a0, a1, 0, 1, 2, 3, 4, 5, 6, 7);
      i32x4 vb = *(const i32x4*)&Bs[cur][nw + t * 16 + ml][pb];
      bfr[t] = __builtin_shufflevector(vb, z, 0, 1, 2, 3, 4, 5, 6, 7);
    }
#pragma unroll
    for (int mt = 0; mt < 4; ++mt)
#pragma unroll
      for (int nt = 0; nt < 4; ++nt)
        acc[mt][nt] = __builtin_amdgcn_mfma_scale_f32_16x16x128_f8f6f4(
            af[mt], bfr[nt], acc[mt][nt],
            0, 4, 0, 0x7F7F7F7F, 0, 0x78787878);
    __syncthreads();
  }

  // Fused epilogue: h = relu(acc + b3[col]); p[row] += h * W4[col];
  // shfl-reduce over 16 lanes sharing each row; lane 0 atomicAdds.
  float bv[4], w4v[4];
#pragma unroll
  for (int nt = 0; nt < 4; ++nt) {
    int col = n0 + nw + nt * 16 + ml;
    bv[nt] = bias[col];
    w4v[nt] = W4[col];
  }
  int rbase = kg * 4;
#pragma unroll
  for (int mt = 0; mt < 4; ++mt) {
#pragma unroll
    for (int r = 0; r < 4; ++r) {
      float p = 0.f;
#pragma unroll
      for (int nt = 0; nt < 4; ++nt) {
        float v = acc[mt][nt][r] + bv[nt];
        v = v > 0.f ? v : 0.f;
        p += v * w4v[nt];
      }
#pragma unroll
      for (int m = 1; m < 16; m <<= 1) p += __shfl_xor(p, m);
      if (ml == 0)
        atomicAdd(&dotacc[m0 + mw + mt * 16 + rbase + r], p);
    }
  }
}

// ---------------- Stage 4: final — S reduce + sigmoid ----------------------
__global__ void final_out(const float* __restrict__ part,
                          const float* __restrict__ dotacc,
                          const float* __restrict__ lin,
                          const float* __restrict__ bias,
                          const float* __restrict__ b4,
                          float* __restrict__ out) {
  __shared__ float ps[4];
  int tid = threadIdx.x;
  float v = 0.f;
  for (int i = tid; i < 4096; i += 256) v += part[i];
#pragma unroll
  for (int m = 32; m; m >>= 1) v += __shfl_xor(v, m);
  if ((tid & 63) == 0) ps[tid >> 6] = v;
  __syncthreads();
  float S = ps[0] + ps[1] + ps[2] + ps[3];
  int i = blockIdx.x * 256 + tid;
  float z = dotacc[i] + b4[0] + bias[0] + lin[i] + 0.5f * S;
  out[i] = 1.f / (1.f + expf(-z));
}

// ---------------------------------------------------------------------------
extern "C" void kernel_launch(void* const* d_in, const int* in_sizes, int n_in,
                              void* d_out, int out_size, void* d_ws,
                              size_t ws_size, hipStream_t stream) {
  const float* x    = (const float*)d_in[0];
  const float* bias = (const float*)d_in[1];
  const float* fc   = (const float*)d_in[2];
  const float* emb  = (const float*)d_in[3];
  const float* W1   = (const float*)d_in[4];
  const float* b1   = (const float*)d_in[5];
  const float* W2   = (const float*)d_in[6];
  const float* b2   = (const float*)d_in[7];
  const float* W3   = (const float*)d_in[8];
  const float* b3   = (const float*)d_in[9];
  const float* W4   = (const float*)d_in[10];
  const float* b4   = (const float*)d_in[11];
  float* out = (float*)d_out;

  char* ws = (char*)d_ws;
  float* lin    = (float*)(ws + OFF_LIN);
  float* part   = (float*)(ws + OFF_PART);
  float* dacc   = (float*)(ws + OFF_ACC);
  uint8_t* EMBb = (uint8_t*)(ws + OFF_EMB);
  uint8_t* H1   = (uint8_t*)(ws + OFF_H1);
  uint8_t* H2   = (uint8_t*)(ws + OFF_H2);
  uint8_t* W1T  = (uint8_t*)(ws + OFF_W1T);
  uint8_t* W2T  = (uint8_t*)(ws + OFF_W2T);
  uint8_t* W3T  = (uint8_t*)(ws + OFF_W3T);

  prep<<<7696, 256, 0, stream>>>(W1, W2, W3, W1T, W2T, W3T, x, fc, emb, EMBb,
                                 lin, part, dacc);

  gemm_mx_relu<<<2048, 256, 0, stream>>>(EMBb, W1T, b1, H1, 512, 2048, 16);
  gemm_mx_relu<<<1024, 256, 0, stream>>>(H1, W2T, b2, H2, 2048, 1024, 8);
  gemm_mx_dot<<<512, 256, 0, stream>>>(H2, W3T, b3, W4, dacc, 1024, 512, 4);

  final_out<<<64, 256, 0, stream>>>(part, dacc, lin, bias, b4, out);
}

// Round 12
// 173.554 us; speedup vs baseline: 1.0466x; 1.0466x over previous
//
#include <hip/hip_runtime.h>
#include <hip/hip_fp8.h>
#include <cstdint>

// ---------------------------------------------------------------------------
// DeepFM forward, MI355X (R12 = revert to R9 config, best measured: 174.8 us).
//   Stage 1: prep — W1..W3 f32->fp4 W^T (pre-scaled 2^7) + gather (embed fp8,
//            lin, FM partials) + zero mlp-dot accumulator   [one kernel]
//   Stage 2: GEMM1, GEMM2 (A=fp8 acts, B=fp4 weights, 16x16x128 f8f6f4,
//            cbsz=0/blgp=4, BK=256, 2-barrier global_load_lds staging)
//   Stage 3: GEMM3 with fused L4 dot (atomicAdd per sample; H3 never exists)
//   Stage 4: final — redundant-per-block S reduce + sigmoid.  5 nodes.
//
// Pipelining post-mortem (R8/R10/R11): register prefetch, 6-blocks/CU
// occupancy, and LDS double-buffer ALL land at/above the 2-barrier baseline
// — the K-loop drain stall is structural at HIP source level (compiler
// re-inserts conservative waitcnt; m131/m135/m141). Ceiling arithmetic:
// ~100 us harness reset (268 MB ws poison + restores) + ~75 us kernels
// (GEMM MFMA floor 26 us + gather 10 us + the unreachable latency gap).
// ---------------------------------------------------------------------------

typedef float f32x4 __attribute__((ext_vector_type(4)));
typedef int i32x4 __attribute__((ext_vector_type(4)));
typedef int i32x8 __attribute__((ext_vector_type(8)));

#define GLOAD16(gptr, lptr)                                                \
  __builtin_amdgcn_global_load_lds(                                        \
      (const __attribute__((address_space(1))) void*)(gptr),               \
      (__attribute__((address_space(3))) void*)(lptr), 16, 0, 0)

// fp4 e2m1 encode (weights only; RNE; magnitudes 0,.5,1,1.5,2,3,4,6)
__device__ inline uint32_t f2fp4(float v) {
  uint32_t s = (__float_as_uint(v) >> 31) << 3;
  float a = fabsf(v);
  uint32_t m;
  if (a < 0.25f) m = 0;
  else if (a < 0.75f) m = 1;
  else if (a < 1.25f) m = 2;
  else if (a < 1.75f) m = 3;
  else if (a < 2.5f)  m = 4;
  else if (a < 3.5f)  m = 5;
  else if (a < 5.0f)  m = 6;
  else m = 7;
  return s | m;
}

// ---------------- workspace layout (bytes) ---------------------------------
static constexpr size_t OFF_LIN  = 0;                          // 16384 f32
static constexpr size_t OFF_PART = 65536;                      // 4096 f32
static constexpr size_t OFF_ACC  = 98304;                      // 16384 f32
static constexpr size_t OFF_EMB  = 262144;                     // B*512 fp8
static constexpr size_t OFF_H1   = OFF_EMB + 8388608ull;       // B*2048 fp8
static constexpr size_t OFF_H2   = OFF_H1 + 33554432ull;       // B*1024 fp8
static constexpr size_t OFF_W1T  = OFF_H2 + 16777216ull;       // 2048*512 fp4
static constexpr size_t OFF_W2T  = OFF_W1T + 524288ull;        // 1024*2048 fp4
static constexpr size_t OFF_W3T  = OFF_W2T + 1048576ull;       // 512*1024 fp4

// ---------------- Stage 1: fused prep (transpose + gather + zero) ----------
__global__ void prep(const float* __restrict__ W1, const float* __restrict__ W2,
                     const float* __restrict__ W3, uint8_t* __restrict__ W1T,
                     uint8_t* __restrict__ W2T, uint8_t* __restrict__ W3T,
                     const float* __restrict__ x, const float* __restrict__ fc,
                     const float* __restrict__ emb, uint8_t* __restrict__ ebf,
                     float* __restrict__ lin, float* __restrict__ partials,
                     float* __restrict__ dotacc) {
  __shared__ __align__(16) float smem[32 * 33];
  int blk = blockIdx.x;
  int tid = threadIdx.x;
  if (blk < 3584) {  // ---- transpose ----
    const float* W;
    uint8_t* WT;
    int K, N, bx, by;
    if (blk < 1024) {        // W1: K=512, N=2048
      W = W1; WT = W1T; K = 512; N = 2048; bx = blk & 63; by = blk >> 6;
    } else if (blk < 3072) { // W2: K=2048, N=1024
      int t = blk - 1024;
      W = W2; WT = W2T; K = 2048; N = 1024; bx = t & 31; by = t >> 5;
    } else {                 // W3: K=1024, N=512
      int t = blk - 3072;
      W = W3; WT = W3T; K = 1024; N = 512; bx = t & 15; by = t >> 4;
    }
    int tx = tid & 31, ty = tid >> 5;
    int n0 = bx * 32, k0 = by * 32;
#pragma unroll
    for (int i = ty; i < 32; i += 8)
      smem[i * 33 + tx] = W[(size_t)(k0 + i) * N + n0 + tx];
    __syncthreads();
    if (tx < 16) {
#pragma unroll
      for (int i = ty; i < 32; i += 8) {
        uint32_t lo = f2fp4(smem[(2 * tx) * 33 + i] * 128.f);
        uint32_t hi = f2fp4(smem[(2 * tx + 1) * 33 + i] * 128.f);
        WT[(size_t)(n0 + i) * (K >> 1) + (k0 >> 1) + tx] =
            (uint8_t)(lo | (hi << 4));
      }
    }
  } else if (blk < 7680) {  // ---- gather ----
    int gb = blk - 3584;
    int wv = tid >> 6, lane = tid & 63;
    int b = gb * 4 + wv;
    int f = lane >> 4;
    int idx = (int)x[b * 4 + f];               // raw index (NO offset) for emb
    const float* row = emb + (size_t)idx * 128 + (lane & 15) * 8;
    float4 v0 = ((const float4*)row)[0];
    float4 v1 = ((const float4*)row)[1];
    float s = v0.x + v0.y + v0.z + v0.w + v1.x + v1.y + v1.z + v1.w;
    float q = v0.x * v0.x + v0.y * v0.y + v0.z * v0.z + v0.w * v0.w +
              v1.x * v1.x + v1.y * v1.y + v1.z * v1.z + v1.w * v1.w;

    int lo = 0, hi = 0;
    lo = __builtin_amdgcn_cvt_pk_fp8_f32(v0.x, v0.y, lo, false);
    lo = __builtin_amdgcn_cvt_pk_fp8_f32(v0.z, v0.w, lo, true);
    hi = __builtin_amdgcn_cvt_pk_fp8_f32(v1.x, v1.y, hi, false);
    hi = __builtin_amdgcn_cvt_pk_fp8_f32(v1.z, v1.w, hi, true);
    int2 pk = make_int2(lo, hi);
    *(int2*)(ebf + (size_t)b * 512 + lane * 8) = pk;   // 8 B/lane coalesced

    float lp = 0.f;
    if ((lane & 15) == 0) {                    // fc lookup USES offsets
      int off = (f == 1) ? 31360 : (f == 2) ? 38167 : (f == 3) ? 38185 : 0;
      lp = fc[idx + off];
    }
#pragma unroll
    for (int m = 32; m; m >>= 1) {
      s += __shfl_xor(s, m);
      q += __shfl_xor(q, m);
      lp += __shfl_xor(lp, m);
    }
    float* pt = smem;
    if (lane == 0) {
      lin[b] = lp;
      pt[wv] = s * s - q;                      // per-sample FM term
    }
    __syncthreads();
    if (tid == 0) partials[gb] = pt[0] + pt[1] + pt[2] + pt[3];
  } else {  // ---- zero mlp-dot accumulator (16 blocks) ----
    int zb = blk - 7680;
    ((float4*)dotacc)[zb * 256 + tid] = make_float4(0.f, 0.f, 0.f, 0.f);
  }
}

// ---------------- Stage 2: mixed GEMM, C = relu(A*B + bias) ----------------
// A fp8 (stride K B), BT fp4 (stride K/2 B), C fp8 (stride N B).
// 128x128 tile, BK=256. As rows 256 B (16-chunk XOR swizzle), Bs rows 128 B
// (8-chunk XOR swizzle) — verified conflict-free. global_load_lds width=16.
// MFMA 16x16x128 f8f6f4: cbsz=0 (fp8 A), blgp=4 (fp4 B), scale_a=1,
// scale_b=2^-7 (undoes W pre-scale). XCD swizzle: A-strip blocks share bid%8.
__global__ __launch_bounds__(256) void gemm_mx_relu(
    const uint8_t* __restrict__ A, const uint8_t* __restrict__ BT,
    const float* __restrict__ bias, uint8_t* __restrict__ C, int K, int N,
    int GX) {
  __shared__ __align__(16) uint8_t As[128][256];   // 32 KB
  __shared__ __align__(16) uint8_t Bs[128][128];   // 16 KB
  int bid = blockIdx.x;
  int by = (bid & 7) + ((bid >> 3) / GX) * 8;
  int bx = (bid >> 3) & (GX - 1);
  int tid = threadIdx.x;
  int wv = tid >> 6, lane = tid & 63;
  int m0 = by * 128, n0 = bx * 128;
  int mw = (wv >> 1) * 64, nw = (wv & 1) * 64;
  int ml = lane & 15, kg = lane >> 4;
  int Kb2 = K >> 1;
  int arow = lane >> 4;                        // A: 4-row staging groups
  int brow = lane >> 3;                        // B: 8-row staging groups
  int bcol = ((lane & 7) ^ brow) * 16;

  f32x4 acc[4][4];
#pragma unroll
  for (int i = 0; i < 4; ++i)
#pragma unroll
    for (int j = 0; j < 4; ++j) acc[i][j] = (f32x4){0.f, 0.f, 0.f, 0.f};

  for (int kt = 0; kt < K; kt += 256) {
#pragma unroll
    for (int r = 0; r < 8; ++r) {              // A: 32 groups of 4 rows
      int g = r * 4 + wv;
      int trow = 4 * g + arow;
      int acol = ((lane & 15) ^ (trow & 15)) * 16;
      const uint8_t* ga = A + (size_t)(m0 + trow) * K + kt + acol;
      GLOAD16(ga, &As[4 * g][0]);
    }
#pragma unroll
    for (int r = 0; r < 4; ++r) {              // B: 16 groups of 8 rows
      int g = r * 4 + wv;
      const uint8_t* gb =
          BT + (size_t)(n0 + 8 * g + brow) * Kb2 + (kt >> 1) + bcol;
      GLOAD16(gb, &Bs[8 * g][0]);
    }
    __syncthreads();

    i32x4 z = (i32x4){0, 0, 0, 0};
#pragma unroll
    for (int j = 0; j < 2; ++j) {              // two 128-elem k-halves
      int c0 = 8 * j + 2 * kg;
      int pa0 = (c0 ^ ml) * 16;
      int pa1 = ((c0 + 1) ^ ml) * 16;
      int pb = ((4 * j + kg) ^ (ml & 7)) * 16;
      i32x8 af[4], bfr[4];
#pragma unroll
      for (int t = 0; t < 4; ++t) {
        int ra = mw + t * 16 + ml;
        i32x4 a0 = *(const i32x4*)&As[ra][pa0];
        i32x4 a1 = *(const i32x4*)&As[ra][pa1];
        af[t] = __builtin_shufflevector(a0, a1, 0, 1, 2, 3, 4, 5, 6, 7);
        i32x4 vb = *(const i32x4*)&Bs[nw + t * 16 + ml][pb];
        bfr[t] = __builtin_shufflevector(vb, z, 0, 1, 2, 3, 4, 5, 6, 7);
      }
#pragma unroll
      for (int mt = 0; mt < 4; ++mt)
#pragma unroll
        for (int nt = 0; nt < 4; ++nt)
          acc[mt][nt] = __builtin_amdgcn_mfma_scale_f32_16x16x128_f8f6f4(
              af[mt], bfr[nt], acc[mt][nt],
              /*cbsz=fp8*/ 0, /*blgp=fp4*/ 4,
              0, 0x7F7F7F7F, 0, 0x78787878);
    }
    __syncthreads();
  }

  // Epilogue: C/D layout col=lane&15, row=(lane>>4)*4+reg.
  int rbase = kg * 4;
#pragma unroll
  for (int nt = 0; nt < 4; ++nt) {
    int col = n0 + nw + nt * 16 + ml;
    float bv = bias[col];
#pragma unroll
    for (int mt = 0; mt < 4; ++mt) {
      int row = m0 + mw + mt * 16 + rbase;
      float v0 = acc[mt][nt][0] + bv, v1 = acc[mt][nt][1] + bv;
      float v2 = acc[mt][nt][2] + bv, v3 = acc[mt][nt][3] + bv;
      v0 = v0 > 0.f ? v0 : 0.f;
      v1 = v1 > 0.f ? v1 : 0.f;
      v2 = v2 > 0.f ? v2 : 0.f;
      v3 = v3 > 0.f ? v3 : 0.f;
      int w01 = __builtin_amdgcn_cvt_pk_fp8_f32(v0, v1, 0, false);
      int w23 = __builtin_amdgcn_cvt_pk_fp8_f32(v2, v3, 0, false);
      C[(size_t)(row + 0) * N + col] = (uint8_t)(w01 & 0xFF);
      C[(size_t)(row + 1) * N + col] = (uint8_t)((w01 >> 8) & 0xFF);
      C[(size_t)(row + 2) * N + col] = (uint8_t)(w23 & 0xFF);
      C[(size_t)(row + 3) * N + col] = (uint8_t)((w23 >> 8) & 0xFF);
    }
  }
}

// ---------------- Stage 3: GEMM3 + fused L4 partial dot --------------------
__global__ __launch_bounds__(256) void gemm_mx_dot(
    const uint8_t* __restrict__ A, const uint8_t* __restrict__ BT,
    const float* __restrict__ bias, const float* __restrict__ W4,
    float* __restrict__ dotacc, int K, int N, int GX) {
  __shared__ __align__(16) uint8_t As[128][256];
  __shared__ __align__(16) uint8_t Bs[128][128];
  int bid = blockIdx.x;
  int by = (bid & 7) + ((bid >> 3) / GX) * 8;
  int bx = (bid >> 3) & (GX - 1);
  int tid = threadIdx.x;
  int wv = tid >> 6, lane = tid & 63;
  int m0 = by * 128, n0 = bx * 128;
  int mw = (wv >> 1) * 64, nw = (wv & 1) * 64;
  int ml = lane & 15, kg = lane >> 4;
  int Kb2 = K >> 1;
  int arow = lane >> 4;
  int brow = lane >> 3;
  int bcol = ((lane & 7) ^ brow) * 16;

  f32x4 acc[4][4];
#pragma unroll
  for (int i = 0; i < 4; ++i)
#pragma unroll
    for (int j = 0; j < 4; ++j) acc[i][j] = (f32x4){0.f, 0.f, 0.f, 0.f};

  for (int kt = 0; kt < K; kt += 256) {
#pragma unroll
    for (int r = 0; r < 8; ++r) {
      int g = r * 4 + wv;
      int trow = 4 * g + arow;
      int acol = ((lane & 15) ^ (trow & 15)) * 16;
      const uint8_t* ga = A + (size_t)(m0 + trow) * K + kt + acol;
      GLOAD16(ga, &As[4 * g][0]);
    }
#pragma unroll
    for (int r = 0; r < 4; ++r) {
      int g = r * 4 + wv;
      const uint8_t* gb =
          BT + (size_t)(n0 + 8 * g + brow) * Kb2 + (kt >> 1) + bcol;
      GLOAD16(gb, &Bs[8 * g][0]);
    }
    __syncthreads();

    i32x4 z = (i32x4){0, 0, 0, 0};
#pragma unroll
    for (int j = 0; j < 2; ++j) {
      int c0 = 8 * j + 2 * kg;
      int pa0 = (c0 ^ ml) * 16;
      int pa1 = ((c0 + 1) ^ ml) * 16;
      int pb = ((4 * j + kg) ^ (ml & 7)) * 16;
      i32x8 af[4], bfr[4];
#pragma unroll
      for (int t = 0; t < 4; ++t) {
        int ra = mw + t * 16 + ml;
        i32x4 a0 = *(const i32x4*)&As[ra][pa0];
        i32x4 a1 = *(const i32x4*)&As[ra][pa1];
        af[t] = __builtin_shufflevector(a0, a1, 0, 1, 2, 3, 4, 5, 6, 7);
        i32x4 vb = *(const i32x4*)&Bs[nw + t * 16 + ml][pb];
        bfr[t] = __builtin_shufflevector(vb, z, 0, 1, 2, 3, 4, 5, 6, 7);
      }
#pragma unroll
      for (int mt = 0; mt < 4; ++mt)
#pragma unroll
        for (int nt = 0; nt < 4; ++nt)
          acc[mt][nt] = __builtin_amdgcn_mfma_scale_f32_16x16x128_f8f6f4(
              af[mt], bfr[nt], acc[mt][nt],
              0, 4, 0, 0x7F7F7F7F, 0, 0x78787878);
    }
    __syncthreads();
  }

  // Fused epilogue: h = relu(acc + b3[col]); p[row] += h * W4[col];
  // shfl-reduce over the 16 lanes sharing each row; lane 0 atomicAdds.
  float bv[4], w4v[4];
#pragma unroll
  for (int nt = 0; nt < 4; ++nt) {
    int col = n0 + nw + nt * 16 + ml;
    bv[nt] = bias[col];
    w4v[nt] = W4[col];
  }
  int rbase = kg * 4;
#pragma unroll
  for (int mt = 0; mt < 4; ++mt) {
#pragma unroll
    for (int r = 0; r < 4; ++r) {
      float p = 0.f;
#pragma unroll
      for (int nt = 0; nt < 4; ++nt) {
        float v = acc[mt][nt][r] + bv[nt];
        v = v > 0.f ? v : 0.f;
        p += v * w4v[nt];
      }
#pragma unroll
      for (int m = 1; m < 16; m <<= 1) p += __shfl_xor(p, m);
      if (ml == 0)
        atomicAdd(&dotacc[m0 + mw + mt * 16 + rbase + r], p);
    }
  }
}

// ---------------- Stage 4: final — S reduce + sigmoid ----------------------
__global__ void final_out(const float* __restrict__ part,
                          const float* __restrict__ dotacc,
                          const float* __restrict__ lin,
                          const float* __restrict__ bias,
                          const float* __restrict__ b4,
                          float* __restrict__ out) {
  __shared__ float ps[4];
  int tid = threadIdx.x;
  float v = 0.f;
  for (int i = tid; i < 4096; i += 256) v += part[i];
#pragma unroll
  for (int m = 32; m; m >>= 1) v += __shfl_xor(v, m);
  if ((tid & 63) == 0) ps[tid >> 6] = v;
  __syncthreads();
  float S = ps[0] + ps[1] + ps[2] + ps[3];
  int i = blockIdx.x * 256 + tid;
  float z = dotacc[i] + b4[0] + bias[0] + lin[i] + 0.5f * S;
  out[i] = 1.f / (1.f + expf(-z));
}

// ---------------------------------------------------------------------------
extern "C" void kernel_launch(void* const* d_in, const int* in_sizes, int n_in,
                              void* d_out, int out_size, void* d_ws,
                              size_t ws_size, hipStream_t stream) {
  const float* x    = (const float*)d_in[0];
  const float* bias = (const float*)d_in[1];
  const float* fc   = (const float*)d_in[2];
  const float* emb  = (const float*)d_in[3];
  const float* W1   = (const float*)d_in[4];
  const float* b1   = (const float*)d_in[5];
  const float* W2   = (const float*)d_in[6];
  const float* b2   = (const float*)d_in[7];
  const float* W3   = (const float*)d_in[8];
  const float* b3   = (const float*)d_in[9];
  const float* W4   = (const float*)d_in[10];
  const float* b4   = (const float*)d_in[11];
  float* out = (float*)d_out;

  char* ws = (char*)d_ws;
  float* lin    = (float*)(ws + OFF_LIN);
  float* part   = (float*)(ws + OFF_PART);
  float* dacc   = (float*)(ws + OFF_ACC);
  uint8_t* EMBb = (uint8_t*)(ws + OFF_EMB);
  uint8_t* H1   = (uint8_t*)(ws + OFF_H1);
  uint8_t* H2   = (uint8_t*)(ws + OFF_H2);
  uint8_t* W1T  = (uint8_t*)(ws + OFF_W1T);
  uint8_t* W2T  = (uint8_t*)(ws + OFF_W2T);
  uint8_t* W3T  = (uint8_t*)(ws + OFF_W3T);

  prep<<<7696, 256, 0, stream>>>(W1, W2, W3, W1T, W2T, W3T, x, fc, emb, EMBb,
                                 lin, part, dacc);

  gemm_mx_relu<<<2048, 256, 0, stream>>>(EMBb, W1T, b1, H1, 512, 2048, 16);
  gemm_mx_relu<<<1024, 256, 0, stream>>>(H1, W2T, b2, H2, 2048, 1024, 8);
  gemm_mx_dot<<<512, 256, 0, stream>>>(H2, W3T, b3, W4, dacc, 1024, 512, 4);

  final_out<<<64, 256, 0, stream>>>(part, dacc, lin, bias, b4, out);
}